// Round 19
// baseline (25.689 us; speedup 1.0000x reference)
//
#include <hip/hip_runtime.h>

// CTC batch cost (Keras ctc_batch_cost), B=256, T=512, C=128, L=64.
// 256 blocks x 192 threads: wave0 = consumer (recurrence), waves1-2 = HALF
// producers (wave1 rows 0-15, wave2 rows 16-31 of every chunk) -> producer
// critical path per interval halves vs r13. Consumer identical to r13/r18:
// blank-normalized linear domain, 0.5/step decay folded into ql, per-lane
// pow2 exponent, trigger renorm (wave-vote), static-index-only loops.
// Each producer: stages its half-chunk (8 global_load_lds, per-wave vmcnt),
// computes ql = (pl+eps)*rcp(pb+eps)*0.5, b128 writes; own llg half-sum.
// Consumer releases ql buffer at interval start (loads to regs, barrier),
// so producers have a full interval of slack writing the other buffer.

#define B_ 256
#define T_ 512
#define C_ 128
#define L_ 64
#define BLANK_ 127
#define EPSF (1e-7f)
#define CHUNK 32
#define HROWS 16           // rows per producer half
#define QSTR 36            // per-lane ql stride (dwords); 144B, 16B-aligned
#define LN2F 0.6931471805599453f

#define EXP2(x) __builtin_amdgcn_exp2f(x)   // v_exp_f32 (base-2)
#define LOG2(x) __builtin_amdgcn_logf(x)    // v_log_f32 (base-2)

__device__ __forceinline__ float lse2_2(float a, float b) {
    float m = fmaxf(a, b);
    float d = fminf(a, b) - m;
    return m + LOG2(1.0f + EXP2(d));
}

__device__ __forceinline__ float dppf(float x) {  // lane i <- i-1; lane0 <- 0
    return __int_as_float(__builtin_amdgcn_update_dpp(
        0, __float_as_int(x), 0x138, 0xf, 0xf, false));
}
__device__ __forceinline__ int dppi(int x) {
    return __builtin_amdgcn_update_dpp(0, x, 0x138, 0xf, 0xf, false);
}

// stage rows [ho, ho+16) of one chunk: 8 x (64 lanes x 16B)
__device__ __forceinline__ void stage_half(const float* gsrc, float* ldst,
                                           int lane, int ho) {
    const int base = ho * C_;
#pragma unroll
    for (int i = 0; i < 8; ++i) {
        __builtin_amdgcn_global_load_lds(
            (const __attribute__((address_space(1))) void*)
                (gsrc + base + i * 256 + lane * 4),
            (__attribute__((address_space(3))) void*)(ldst + base + i * 256),
            16, 0, 0);
    }
}

// produce ql rows [ho, ho+16) of one chunk into qd (+lane*QSTR)
__device__ __forceinline__ void produce_half(const float* __restrict__ rk,
        float* __restrict__ qd, int lane, int label, int ho,
        int t0, int tend, float& llg)
{
    const float pbv = rk[((lane & 15) + ho) * C_ + BLANK_] + EPSF;
    const float rpb = __builtin_amdgcn_rcpf(pbv) * 0.5f;   // 0.5 = decay
    const int t = t0 + ho + (lane & 15);
    const bool lgv = (lane < 16) && (t >= 1) && (t < tend);
    llg += lgv ? LOG2(pbv) : 0.0f;
#pragma unroll
    for (int k = 0; k < HROWS / 4; ++k) {
        float q[4];
#pragma unroll
        for (int j = 0; j < 4; ++j) {
            const int r = ho + 4 * k + j;
            const float pl = rk[r * C_ + label] + EPSF;
            const float rb = __int_as_float(
                __builtin_amdgcn_readlane(__float_as_int(rpb), 4 * k + j));
            q[j] = pl * rb;                   // 0.5*(pl+eps)/(pb+eps)
        }
        *reinterpret_cast<float4*>(qd + lane * QSTR + ho + 4 * k) =
            make_float4(q[0], q[1], q[2], q[3]);
    }
}

// trigger test + rare renorm block (wave-uniform branch)
template<bool HAS128>
__device__ __forceinline__ void maybe_renorm(float& A0, float& A1, float& A2,
                                             int& e, float& sch, float& kq,
                                             float skipf2) {
    float m2 = fmaxf(A0, A1);
    if (HAS128) m2 = fmaxf(m2, A2);
    const bool out = (m2 > 16777216.0f) ||
                     ((m2 < 5.9604644775390625e-8f) && (m2 > 0.0f));  // 2^+-24
    if (__any(out)) {
        const float mm = (m2 == 0.0f) ? 1.0f : m2;
        const int eb = __float_as_int(mm) >> 23;           // biased exp
        const float s = __int_as_float((254 - eb) << 23);  // exact 2^(127-eb)
        A0 *= s; A1 *= s;
        if (HAS128) A2 *= s;
        e += eb - 127;
        const int ep = dppi(e);
        int d = ep - e;
        d = d < -125 ? -125 : d;
        d = d > 127 ? 127 : d;
        sch = __int_as_float((d + 126) << 23);             // 0.5*2^d
        kq = skipf2 * sch;
    }
}

template<bool HAS128>
__device__ __forceinline__ void step(float& A0, float& A1, float& A2,
                                     float sch, float kq, float ql) {
    const float s1 = dppf(A1);                // cross-lane: A1 of lane-1
    const float Y  = A1 + A0;                 // runs parallel with dpp
    const float A2n = HAS128 ? (A2 + A1) * 0.5f : A2;
    const float P1 = s1 * sch;
    const float A1n = fmaf(kq, s1, Y) * ql;   // chain: dpp -> fma -> mul
    const float A0n = fmaf(A0, 0.5f, P1);
    A0 = A0n; A1 = A1n;
    if (HAS128) A2 = A2n;
}

template<bool HAS128>
__device__ __forceinline__ void consumer_run(const float (*qlb)[64 * QSTR],
        const float* extra, int lane, int lab, int tend, int nmax,
        float skipf2, float* out, int b)
{
    float A0 = 0.0f, A1 = 0.0f, A2 = 0.0f;
    float sch = 0.5f, kq = skipf2 * 0.5f;
    int e = 0;

    for (int c = 0; c < nmax; ++c) {
        const float* qb = &qlb[c & 1][lane * QSTR];
        float q[CHUNK];
#pragma unroll
        for (int k = 0; k < CHUNK / 4; ++k) {
            const float4 t4 = *reinterpret_cast<const float4*>(qb + 4 * k);
            q[4*k+0] = t4.x; q[4*k+1] = t4.y;
            q[4*k+2] = t4.z; q[4*k+3] = t4.w;
        }
        asm volatile("s_waitcnt lgkmcnt(0)" ::: "memory");
        __builtin_amdgcn_s_barrier();          // release buffer to producers
        __builtin_amdgcn_sched_barrier(0);

        const int rem = tend - c * CHUNK;
        if (c == 0) {
            A0 = (lane == 0) ? extra[1] : 0.0f;   // t=0 init (raw, no decay)
            A1 = (lane == 0) ? extra[0] : 0.0f;
#pragma unroll
            for (int u = 1; u < CHUNK; ++u) {     // static indices only
                step<HAS128>(A0, A1, A2, sch, kq, q[u]);
                if ((u & 3) == 3)
                    maybe_renorm<HAS128>(A0, A1, A2, e, sch, kq, skipf2);
            }
        } else if (rem >= CHUNK) {
#pragma unroll
            for (int u = 0; u < CHUNK; ++u) {
                step<HAS128>(A0, A1, A2, sch, kq, q[u]);
                if ((u & 3) == 3)
                    maybe_renorm<HAS128>(A0, A1, A2, e, sch, kq, skipf2);
            }
        } else {
            // GUARDED, fully unrolled: no dynamic q[] index, wave-uniform sel
#pragma unroll
            for (int u = 0; u < CHUNK; ++u) {
                const float A0o = A0, A1o = A1, A2o = A2;
                step<HAS128>(A0, A1, A2, sch, kq, q[u]);
                const bool v = u < rem;
                A0 = v ? A0 : A0o; A1 = v ? A1 : A1o;
                if (HAS128) A2 = v ? A2 : A2o;
                if ((u & 3) == 3)                  // value-preserving: no guard
                    maybe_renorm<HAS128>(A0, A1, A2, e, sch, kq, skipf2);
            }
        }
    }
    __builtin_amdgcn_s_barrier();                 // BF: lg halves ready
    const float lg = extra[2] + extra[3];
    const float ef = (float)e + lg + (float)(tend - 1);   // decay accounting
    const float l0 = LOG2(A0) + ef;
    const float l1 = LOG2(A1) + ef;
    const float a_prev = __shfl(l1, lab - 1);             // state 2*lab-1
    float a_last;
    if (HAS128) {
        const float l2 = LOG2(A2) + ef;
        a_last = __shfl(l2, 63);                          // state 128
    } else {
        a_last = __shfl(l0, lab);                         // state 2*lab
    }
    if (lane == 0) out[b] = -LN2F * lse2_2(a_last, a_prev);
}

__global__ __launch_bounds__(192) void ctc_fwd_kernel(
    const int* __restrict__ y_true, const float* __restrict__ y_pred,
    const int* __restrict__ input_len, const int* __restrict__ label_len,
    float* __restrict__ out)
{
    __shared__ __align__(16) float raw[2][CHUNK * C_];     // 32 KB
    __shared__ __align__(16) float qlb[2][64 * QSTR];      // 18.4 KB
    __shared__ float extra[4];      // [0]=A1init [1]=A0init [2..3]=llg halves

    const int b = blockIdx.x;
    const int tid = threadIdx.x;
    const int lane = tid & 63;
    const int wid = tid >> 6;                              // 0=consumer, 1..2
    const float* __restrict__ Pg = y_pred + (size_t)b * T_ * C_;
    const int label = y_true[b * L_ + lane];
    const int in_len = input_len[b];
    const int tend = in_len < T_ ? in_len : T_;            // >= 256
    const int nmax = (tend + CHUNK - 1) / CHUNK;           // 8..16

    if (wid > 0) {
        // --------------- producer wave (pi=0: rows 0-15, pi=1: 16-31) --------
        const int pi = wid - 1;
        const int ho = pi * HROWS;
        float llg = 0.0f;
        stage_half(Pg, &raw[0][0], lane, ho);              // chunk 0 half
        stage_half(Pg + CHUNK * C_, &raw[1][0], lane, ho); // chunk 1 half
        asm volatile("s_waitcnt vmcnt(8)" ::: "memory");   // chunk0 half landed
        produce_half(&raw[0][0], &qlb[0][0], lane, label, ho, 0, tend, llg);
        if (pi == 0 && lane == 0) {
            extra[0] = raw[0][label]  + EPSF;              // A1 init (s=1)
            extra[1] = raw[0][BLANK_] + EPSF;              // A0 init (s=0)
        }
        asm volatile("s_waitcnt lgkmcnt(0)" ::: "memory");
        __builtin_amdgcn_s_barrier();                      // B0
        for (int c = 0; c < nmax; ++c) {
            if (c + 2 < nmax)
                stage_half(Pg + (size_t)(c + 2) * CHUNK * C_,
                           &raw[c & 1][0], lane, ho);
            if (c + 1 < nmax) {
                if (c + 2 < nmax) asm volatile("s_waitcnt vmcnt(8)" ::: "memory");
                else              asm volatile("s_waitcnt vmcnt(0)" ::: "memory");
                produce_half(&raw[(c + 1) & 1][0], &qlb[(c + 1) & 1][0],
                             lane, label, ho, (c + 1) * CHUNK, tend, llg);
                asm volatile("s_waitcnt lgkmcnt(0)" ::: "memory");
            }
            __builtin_amdgcn_s_barrier();                  // end of interval c
        }
#pragma unroll
        for (int off = 8; off >= 1; off >>= 1) llg += __shfl_xor(llg, off);
        if (lane == 0) extra[2 + pi] = llg;                // my half's lg
        asm volatile("s_waitcnt lgkmcnt(0)" ::: "memory");
        __builtin_amdgcn_s_barrier();                      // BF
    } else {
        // ------------------------- consumer (wave 0) -------------------------
        const int lprev = __shfl_up(label, 1);
        const float skipf2 = (lane > 0 && label != lprev) ? 2.0f : 0.0f;
        const int lab = label_len[b];
        __builtin_amdgcn_s_barrier();                      // B0
        if (lab == L_)
            consumer_run<true >(qlb, extra, lane, lab, tend, nmax, skipf2, out, b);
        else
            consumer_run<false>(qlb, extra, lane, lab, tend, nmax, skipf2, out, b);
    }
}

extern "C" void kernel_launch(void* const* d_in, const int* in_sizes, int n_in,
                              void* d_out, int out_size, void* d_ws, size_t ws_size,
                              hipStream_t stream) {
    const int*   y_true    = (const int*)d_in[0];
    const float* y_pred    = (const float*)d_in[1];
    const int*   input_len = (const int*)d_in[2];
    const int*   label_len = (const int*)d_in[3];
    float* out = (float*)d_out;

    ctc_fwd_kernel<<<B_, 192, 0, stream>>>(y_true, y_pred, input_len, label_len, out);
}